// Round 3
// baseline (1298.103 us; speedup 1.0000x reference)
//
#include <hip/hip_runtime.h>
#include <math.h>

#define N_NODES 100000
#define N_EDGES 3200000
#define N_FEAT  512
#define N_HID   256
#define N_CLASS 40
#define K_HOPS  10

#define CAP        80                   // bucket capacity (Poisson(32); P(>80)~1e-11)

// two-phase binned build
#define BIN_SHIFT  11
#define NBIN       49                   // ceil(100000 / 2048)
#define NBIN_PAD   56                   // multiple of 8 -> bin b always on XCD b&7
#define BINCAP     68000                // mean 65536, sigma ~253 -> +9.7 sigma
#define CHUNK1     4096                 // edges per phase-1 block
#define CHUNK2     4096                 // records per phase-2 block
#define CPB2       17                   // 17*4096 = 69632 >= BINCAP

typedef __attribute__((ext_vector_type(8))) short short8;
typedef __attribute__((ext_vector_type(4))) unsigned short ushort4v;
typedef __attribute__((ext_vector_type(4))) float float4v;
typedef unsigned long long u64;

__device__ inline short f2bf(float f)
{
    union { float f; unsigned u; } v; v.f = f;
    unsigned r = v.u + 0x7FFF + ((v.u >> 16) & 1);   // RNE
    return (short)(r >> 16);
}

__device__ inline float bf2f(unsigned short u)
{
    union { unsigned u; float f; } v; v.u = (unsigned)u << 16;
    return v.f;
}

// ---------------- weight packing (once per launch, trivial) ----------------
__global__ void pack_w1(const float* __restrict__ W1, short* __restrict__ W1p)
{
    const int id = blockIdx.x * 256 + threadIdx.x;   // 0..4095
    const int kb = id >> 8, n = id & 255;
    short tmp[32];
#pragma unroll
    for (int kl = 0; kl < 32; ++kl)
        tmp[kl] = f2bf(W1[(size_t)(kb * 32 + kl) * N_HID + n]);
    short8* dst = (short8*)&W1p[id * 32];
#pragma unroll
    for (int j = 0; j < 4; ++j) dst[j] = *(short8*)&tmp[j * 8];
}

__global__ void pack_w2(const float* __restrict__ W2, short* __restrict__ W2p)
{
    const int id = blockIdx.x * 256 + threadIdx.x;
    if (id >= 8 * 48) return;
    const int kb = id / 48, n = id % 48;
    short tmp[32];
#pragma unroll
    for (int kl = 0; kl < 32; ++kl)
        tmp[kl] = (n < N_CLASS) ? f2bf(W2[(size_t)(kb * 32 + kl) * N_CLASS + n]) : (short)0;
    short8* dst = (short8*)&W2p[id * 32];
#pragma unroll
    for (int j = 0; j < 4; ++j) dst[j] = *(short8*)&tmp[j * 8];
}

// ---- fused MFMA MLP + hop-0 attention:
//   x0 = bf16(relu(feat@W1+b1)@W2 + b2);  acc = sigmoid(x0.Wa+ba) * x0
// Double-buffered A staging: issue next k-tile loads early, MFMA current
// buffer, convert+ds_write late. ONE barrier per k-step.
__global__ __launch_bounds__(256) void mlp_mfma(
    const float* __restrict__ feat, const short* __restrict__ W1p,
    const float* __restrict__ b1, const short* __restrict__ W2p,
    const float* __restrict__ b2, const float* __restrict__ Wa,
    const float* __restrict__ ba,
    unsigned short* __restrict__ x0, float* __restrict__ acc_out)
{
    __shared__ __align__(16) short smem[64 * 264];          // 33792 B
    short* Abuf      = smem;                                // [2][64][32] bf16 (8 KB), phase 1
    short (*Hs)[264] = (short(*)[264])smem;                 // aliased (phase 2)

    const int t    = threadIdx.x;
    const int wave = t >> 6;
    const int lane = t & 63;
    const int q    = lane >> 4;      // quad 0..3
    const int m    = lane & 15;
    const int n0   = blockIdx.x * 64;
    const int colbase = wave * 64;

    // staging mapping: row r = t>>2, k-chunk kq = t&3 (8 consecutive f32)
    const int r_st  = t >> 2;
    const int kq_st = t & 3;
    const int nrow  = n0 + r_st;
    const bool rok  = nrow < N_NODES;
    const float* fp = rok ? &feat[(size_t)nrow * N_FEAT + 8 * kq_st] : feat;

    float4v acc[4][4];
#pragma unroll
    for (int i = 0; i < 4; ++i)
#pragma unroll
        for (int j = 0; j < 4; ++j) acc[i][j] = (float4v)0.f;

    // prologue: stage k-tile 0 into buf 0
    {
        float4 c0 = {0.f,0.f,0.f,0.f}, c1 = {0.f,0.f,0.f,0.f};
        if (rok) { c0 = *(const float4*)fp; c1 = *(const float4*)(fp + 4); }
        short8 st;
        st[0]=f2bf(c0.x); st[1]=f2bf(c0.y); st[2]=f2bf(c0.z); st[3]=f2bf(c0.w);
        st[4]=f2bf(c1.x); st[5]=f2bf(c1.y); st[6]=f2bf(c1.z); st[7]=f2bf(c1.w);
        *(short8*)&Abuf[t * 8] = st;
    }
    __syncthreads();

    for (int kb = 0; kb < 16; ++kb) {
        // issue next tile loads (latency hides under ds_read + MFMA below)
        float4 nv0 = {0.f,0.f,0.f,0.f}, nv1 = {0.f,0.f,0.f,0.f};
        const bool have = (kb + 1) < 16;
        if (have && rok) {
            const float* np = fp + (size_t)(kb + 1) * 32;
            nv0 = *(const float4*)np;
            nv1 = *(const float4*)(np + 4);
        }

        const short* Ar = &Abuf[(kb & 1) * 2048];
        short8 af[4], bfr[4];
#pragma unroll
        for (int rt = 0; rt < 4; ++rt)
            af[rt] = *(const short8*)&Ar[(rt * 16 + m) * 32 + q * 8];
#pragma unroll
        for (int ct = 0; ct < 4; ++ct) {
            const int off = (kb * 256 + colbase + ct * 16 + m) * 32 + q * 8;
            bfr[ct] = *(const short8*)&W1p[off];
        }
#pragma unroll
        for (int rt = 0; rt < 4; ++rt)
#pragma unroll
            for (int ct = 0; ct < 4; ++ct)
                acc[rt][ct] = __builtin_amdgcn_mfma_f32_16x16x32_bf16(
                    af[rt], bfr[ct], acc[rt][ct], 0, 0, 0);

        if (have) {
            short8 st;
            st[0]=f2bf(nv0.x); st[1]=f2bf(nv0.y); st[2]=f2bf(nv0.z); st[3]=f2bf(nv0.w);
            st[4]=f2bf(nv1.x); st[5]=f2bf(nv1.y); st[6]=f2bf(nv1.z); st[7]=f2bf(nv1.w);
            *(short8*)&Abuf[((kb + 1) & 1) * 2048 + t * 8] = st;
        }
        __syncthreads();
    }

    // phase 1 epilogue: H = relu(acc + b1) -> LDS (bf16)
#pragma unroll
    for (int ct = 0; ct < 4; ++ct) {
        const int col = colbase + ct * 16 + m;
        const float bias = b1[col];
#pragma unroll
        for (int rt = 0; rt < 4; ++rt) {
            const float4v d = acc[rt][ct];
#pragma unroll
            for (int r = 0; r < 4; ++r) {
                const float hv = fmaxf(d[r] + bias, 0.f);
                Hs[rt * 16 + q * 4 + r][col] = f2bf(hv);
            }
        }
    }
    __syncthreads();

    float4v acc2[3];
#pragma unroll
    for (int ct = 0; ct < 3; ++ct) acc2[ct] = (float4v)0.f;
#pragma unroll
    for (int kb = 0; kb < 8; ++kb) {
        const short8 a2 = *(const short8*)&Hs[wave * 16 + m][kb * 32 + q * 8];
#pragma unroll
        for (int ct = 0; ct < 3; ++ct) {
            const int off = (kb * 48 + ct * 16 + m) * 32 + q * 8;
            const short8 b2f = *(const short8*)&W2p[off];
            acc2[ct] = __builtin_amdgcn_mfma_f32_16x16x32_bf16(a2, b2f, acc2[ct], 0, 0, 0);
        }
    }

    // epilogue: x0 write + fused hop-0 attention (acc = sigmoid(x.Wa+ba)*x)
    float val[3][4];
#pragma unroll
    for (int ct = 0; ct < 3; ++ct) {
        const int col = ct * 16 + m;
        const bool cok = col < N_CLASS;
        const float bias = cok ? b2[col] : 0.f;
#pragma unroll
        for (int r = 0; r < 4; ++r) val[ct][r] = acc2[ct][r] + bias;
        if (cok) {
#pragma unroll
            for (int r = 0; r < 4; ++r) {
                const int row = n0 + wave * 16 + q * 4 + r;
                if (row < N_NODES)
                    x0[(size_t)row * N_CLASS + col] = (unsigned short)f2bf(val[ct][r]);
            }
        }
    }
    float part[4];
#pragma unroll
    for (int r = 0; r < 4; ++r) {
        float p = 0.f;
#pragma unroll
        for (int ct = 0; ct < 3; ++ct) {
            const int col = ct * 16 + m;
            if (col < N_CLASS) p += val[ct][r] * Wa[col];
        }
        part[r] = p;
    }
#pragma unroll
    for (int o = 1; o <= 8; o <<= 1)
#pragma unroll
        for (int r = 0; r < 4; ++r) part[r] += __shfl_xor(part[r], o);
    const float bb = ba[0];
#pragma unroll
    for (int r = 0; r < 4; ++r) {
        const int row = n0 + wave * 16 + q * 4 + r;
        if (row < N_NODES) {
            const float sc = 1.f / (1.f + expf(-(part[r] + bb)));
#pragma unroll
            for (int ct = 0; ct < 3; ++ct) {
                const int col = ct * 16 + m;
                if (col < N_CLASS)
                    acc_out[(size_t)row * N_CLASS + col] = sc * val[ct][r];
            }
        }
    }
}

// ---------------- build, phase 1: radix-bin edges by row>>11 ----------------
// Record: [w15:15][row:17][col:17] in a u64.
__global__ __launch_bounds__(256) void bin_kernel(
    const int* __restrict__ erow, const int* __restrict__ ecol,
    const float* __restrict__ ew, int* __restrict__ bin_cursor,
    u64* __restrict__ bins)
{
    __shared__ __align__(16) u64 recs[CHUNK1];   // 32 KB
    __shared__ int hist[NBIN], h2[NBIN], lbase[NBIN], adj[NBIN];

    const int t     = threadIdx.x;
    const int cbase = blockIdx.x * CHUNK1;
    const int e0    = cbase + t * 16;
    const bool has  = e0 < N_EDGES;              // N_EDGES % 16 == 0 -> all-or-nothing
    const int chunk_n = min(CHUNK1, N_EDGES - cbase);

    for (int i = t; i < NBIN; i += 256) { hist[i] = 0; h2[i] = 0; }
    __syncthreads();

    int   rows[16], cols[16], w15[16];
    if (has) {
#pragma unroll
        for (int qv = 0; qv < 4; ++qv) {
            const int4   r = *(const int4*)&erow[e0 + qv * 4];
            const int4   c = *(const int4*)&ecol[e0 + qv * 4];
            const float4 w = *(const float4*)&ew[e0 + qv * 4];
            rows[qv*4+0]=r.x; rows[qv*4+1]=r.y; rows[qv*4+2]=r.z; rows[qv*4+3]=r.w;
            cols[qv*4+0]=c.x; cols[qv*4+1]=c.y; cols[qv*4+2]=c.z; cols[qv*4+3]=c.w;
            const float wf[4] = {w.x, w.y, w.z, w.w};
#pragma unroll
            for (int j = 0; j < 4; ++j) {
                int v = (int)(wf[j] * 32767.f + 0.5f);
                w15[qv*4+j] = (v > 32767) ? 32767 : v;
            }
        }
#pragma unroll
        for (int j = 0; j < 16; ++j)
            atomicAdd(&hist[rows[j] >> BIN_SHIFT], 1);
    }
    __syncthreads();

    if (t == 0) {
        int run = 0;
        for (int b = 0; b < NBIN; ++b) { lbase[b] = run; run += hist[b]; }
    }
    __syncthreads();
    if (t < NBIN) {
        const int g = atomicAdd(&bin_cursor[t], hist[t]);
        adj[t] = g - lbase[t];
    }
    __syncthreads();

    if (has) {
#pragma unroll
        for (int j = 0; j < 16; ++j) {
            const int b = rows[j] >> BIN_SHIFT;
            const int p = lbase[b] + atomicAdd(&h2[b], 1);
            recs[p] = ((u64)w15[j] << 34) | ((u64)rows[j] << 17) | (u64)cols[j];
        }
    }
    __syncthreads();

    for (int i = t; i < chunk_n; i += 256) {
        const u64 r   = recs[i];
        const int row = (int)((r >> 17) & 0x1FFFF);
        const int b   = row >> BIN_SHIFT;
        const int di  = adj[b] + i;                 // = gbase + (i - lbase)
        if (di < BINCAP)
            bins[(size_t)b * BINCAP + di] = r;
    }
}

// ---------------- build, phase 2: per-bin scatter into buckets -------------
// blockIdx = chunk*NBIN_PAD + b; NBIN_PAD % 8 == 0 -> bin b on XCD b&7.
__global__ __launch_bounds__(256) void scatter_bins(
    const int* __restrict__ bin_cursor, const u64* __restrict__ bins,
    int* __restrict__ cnt, unsigned int* __restrict__ ebuck)
{
    const int b = blockIdx.x % NBIN_PAD;
    if (b >= NBIN) return;
    const int chunk = blockIdx.x / NBIN_PAD;
    int n = bin_cursor[b];
    if (n > BINCAP) n = BINCAP;
    const int start = chunk * CHUNK2;
    if (start >= n) return;
    const u64* src = &bins[(size_t)b * BINCAP];

#pragma unroll
    for (int j = 0; j < 16; ++j) {
        const int idx = start + j * 256 + threadIdx.x;
        if (idx < n) {
            const u64 r   = src[idx];
            const int col = (int)(r & 0x1FFFF);
            const int row = (int)((r >> 17) & 0x1FFFF);
            const unsigned rec = ((unsigned)(r >> 34) << 17) | (unsigned)col;
            const int pos = atomicAdd(&cnt[row], 1);
            if (pos < CAP)
                ebuck[(size_t)row * CAP + pos] = rec;
        }
    }
}

// ------- one hop: s = segsum(w * xin[col]) fp32 from bf16 gathers;
//         xout = bf16(s); acc += sigmoid(s.Wa+ba) * s
// wave per row; 4 slots x 16 lanes (l<10 active, each loads 8 B = 4 bf16
// classes). Records prefetched with one coalesced load, broadcast via __shfl.
// Slot-reduction: 2 rounds (xor 16, 32) on s[4] = 8 shfl (was 24).
// LAST: log_softmax fused (acc row fully in-register); skips xout/acc stores.
template <bool LAST>
__global__ __launch_bounds__(256) void hop_kernel(
    const int* __restrict__ cnt, const unsigned int* __restrict__ ebuck,
    const unsigned short* __restrict__ xin,
    unsigned short* __restrict__ xout, float* __restrict__ acc,
    const float* __restrict__ Wa, const float* __restrict__ ba,
    float* __restrict__ out)
{
    const int lane = threadIdx.x & 63;
    const int row  = blockIdx.x * 4 + (threadIdx.x >> 6);
    if (row >= N_NODES) return;
    const int  slot = lane >> 4;     // 0..3
    const int  l    = lane & 15;     // 0..15; classes [4l, 4l+4) if l<10
    const bool act  = l < 10;

    int n = cnt[row];
    if (n > CAP) n = CAP;
    const size_t ebase = (size_t)row * CAP;

    unsigned rec_a = (lane < n) ? ebuck[ebase + lane] : 0u;

    float s[4];
#pragma unroll
    for (int j = 0; j < 4; ++j) s[j] = 0.f;

    const int nmain = (n < 64) ? n : 64;
    for (int e = 0; e < nmain; e += 4) {
        const unsigned r = __shfl(rec_a, e + slot);
        const int   col  = (int)(r & 0x1FFFFu);
        const float w    = (float)(r >> 17) * (1.f / 32767.f);
        if (act) {
            const ushort4v v = *(const ushort4v*)&xin[(size_t)col * N_CLASS + l * 4];
#pragma unroll
            for (int j = 0; j < 4; ++j) s[j] += w * bf2f(v[j]);
        }
    }
    for (int e = 64; e < n; e += 4) {           // rare tail (deg > 64)
        const int ee = e + slot;
        unsigned r = 0u;
        if (ee < n) r = ebuck[ebase + ee];
        const int   col = (int)(r & 0x1FFFFu);
        const float w   = (float)(r >> 17) * (1.f / 32767.f);
        if (act) {
            const ushort4v v = *(const ushort4v*)&xin[(size_t)col * N_CLASS + l * 4];
#pragma unroll
            for (int j = 0; j < 4; ++j) s[j] += w * bf2f(v[j]);
        }
    }

    // reduce across the 4 slots (xor bits 4,5)
#pragma unroll
    for (int j = 0; j < 4; ++j) {
        s[j] += __shfl_xor(s[j], 16);
        s[j] += __shfl_xor(s[j], 32);
    }

    // attention score: per-lane partial over its 4 classes, reduce over l
    float tq = 0.f;
    if (act) {
#pragma unroll
        for (int j = 0; j < 4; ++j) tq += s[j] * Wa[l * 4 + j];
    }
#pragma unroll
    for (int o = 1; o <= 8; o <<= 1) tq += __shfl_xor(tq, o);
    const float z  = tq + ba[0];
    const float sc = 1.f / (1.f + expf(-z));

    const bool wr = act && slot == 0;
    if (!LAST) {
        if (wr) {
            ushort4v ov;
#pragma unroll
            for (int j = 0; j < 4; ++j) ov[j] = (unsigned short)f2bf(s[j]);
            *(ushort4v*)&xout[(size_t)row * N_CLASS + l * 4] = ov;

            float4* ap = (float4*)&acc[(size_t)row * N_CLASS + l * 4];
            float4 a = *ap;
            a.x += sc * s[0]; a.y += sc * s[1];
            a.z += sc * s[2]; a.w += sc * s[3];
            *ap = a;
        }
    } else {
        // fused log_softmax: final acc row is in-register across slot-0 lanes
        float av[4] = {0.f, 0.f, 0.f, 0.f};
        float mxl = -INFINITY;
        if (wr) {
            const float4 a = *(const float4*)&acc[(size_t)row * N_CLASS + l * 4];
            av[0] = a.x + sc * s[0]; av[1] = a.y + sc * s[1];
            av[2] = a.z + sc * s[2]; av[3] = a.w + sc * s[3];
            mxl = fmaxf(fmaxf(av[0], av[1]), fmaxf(av[2], av[3]));
        }
        float mx = mxl;
#pragma unroll
        for (int o = 1; o <= 8; o <<= 1) mx = fmaxf(mx, __shfl_xor(mx, o));
        float se = 0.f;
        if (wr)
            se = expf(av[0] - mx) + expf(av[1] - mx) +
                 expf(av[2] - mx) + expf(av[3] - mx);
#pragma unroll
        for (int o = 1; o <= 8; o <<= 1) se += __shfl_xor(se, o);
        if (wr) {
            const float ls = logf(se);
            float4 o4;
            o4.x = av[0] - mx - ls; o4.y = av[1] - mx - ls;
            o4.z = av[2] - mx - ls; o4.w = av[3] - mx - ls;
            *(float4*)&out[(size_t)row * N_CLASS + l * 4] = o4;
        }
    }
}

extern "C" void kernel_launch(void* const* d_in, const int* in_sizes, int n_in,
                              void* d_out, int out_size, void* d_ws, size_t ws_size,
                              hipStream_t stream)
{
    (void)in_sizes; (void)n_in; (void)out_size; (void)ws_size;
    const float* feat = (const float*)d_in[0];
    const int*   erow = (const int*)d_in[1];
    const int*   ecol = (const int*)d_in[2];
    const float* ew   = (const float*)d_in[3];
    const float* W1   = (const float*)d_in[4];
    const float* b1   = (const float*)d_in[5];
    const float* W2   = (const float*)d_in[6];
    const float* b2   = (const float*)d_in[7];
    const float* Wa   = (const float*)d_in[8];
    const float* ba   = (const float*)d_in[9];
    float* out = (float*)d_out;

    char* ws = (char*)d_ws;
    size_t off = 0;
    auto take = [&](size_t bytes) -> char* {
        char* p = ws + off;
        off += (bytes + 255) & ~(size_t)255;
        return p;
    };
    unsigned short* xb0 = (unsigned short*)take((size_t)N_NODES * N_CLASS * 2 + 64);
    unsigned short* xb1 = (unsigned short*)take((size_t)N_NODES * N_CLASS * 2 + 64);
    float*        acc   = (float*)take((size_t)N_NODES * N_CLASS * 4);
    int*          cnt   = (int*)take((size_t)N_NODES * 4);
    int*          bcur  = (int*)take((size_t)NBIN_PAD * 4);
    short*        W1p   = (short*)take((size_t)N_FEAT * N_HID * 2);
    short*        W2p   = (short*)take((size_t)N_HID * 48 * 2);
    unsigned int* ebuck = (unsigned int*)take((size_t)N_NODES * CAP * 4);
    u64*          bins  = (u64*)take((size_t)NBIN * BINCAP * 8);

    hipMemsetAsync(cnt, 0, (size_t)N_NODES * 4, stream);
    hipMemsetAsync(bcur, 0, (size_t)NBIN_PAD * 4, stream);

    pack_w1<<<16, 256, 0, stream>>>(W1, W1p);
    pack_w2<<<2, 256, 0, stream>>>(W2, W2p);
    mlp_mfma<<<(N_NODES + 63) / 64, 256, 0, stream>>>(feat, W1p, b1, W2p, b2,
                                                      Wa, ba, xb0, acc);

    const int nchunk1 = (N_EDGES + CHUNK1 - 1) / CHUNK1;    // 782
    bin_kernel<<<nchunk1, 256, 0, stream>>>(erow, ecol, ew, bcur, bins);
    scatter_bins<<<NBIN_PAD * CPB2, 256, 0, stream>>>(bcur, bins, cnt, ebuck);

    const unsigned short* xin = xb0;
    unsigned short* xout = xb1;
    for (int k = 0; k < K_HOPS - 1; ++k) {
        hop_kernel<false><<<N_NODES / 4, 256, 0, stream>>>(
            cnt, ebuck, xin, xout, acc, Wa, ba, out);
        unsigned short* tmp = (unsigned short*)xin;
        xin  = xout;
        xout = tmp;
    }
    hop_kernel<true><<<N_NODES / 4, 256, 0, stream>>>(
        cnt, ebuck, xin, xout, acc, Wa, ba, out);
}

// Round 4
// 1200.240 us; speedup vs baseline: 1.0815x; 1.0815x over previous
//
#include <hip/hip_runtime.h>
#include <math.h>

#define N_NODES 100000
#define N_EDGES 3200000
#define N_FEAT  512
#define N_HID   256
#define N_CLASS 40
#define K_HOPS  10

#define CAP        80                   // bucket capacity (Poisson(32); P(>80)~1e-11)

// two-phase binned build
#define BIN_SHIFT  11
#define NBIN       49                   // ceil(100000 / 2048)
#define NBIN_PAD   56                   // multiple of 8 -> bin b always on XCD b&7
#define BINCAP     68000                // mean 65536, sigma ~253 -> +9.7 sigma
#define CHUNK1     4096                 // edges per phase-1 block
#define CHUNK2     4096                 // records per phase-2 block
#define CPB2       17                   // 17*4096 = 69632 >= BINCAP

typedef __attribute__((ext_vector_type(8))) short short8;
typedef __attribute__((ext_vector_type(8))) unsigned short ushort8v;
typedef __attribute__((ext_vector_type(4))) float float4v;
typedef unsigned long long u64;

__device__ inline short f2bf(float f)
{
    union { float f; unsigned u; } v; v.f = f;
    unsigned r = v.u + 0x7FFF + ((v.u >> 16) & 1);   // RNE
    return (short)(r >> 16);
}

__device__ inline float bf2f(unsigned short u)
{
    union { unsigned u; float f; } v; v.u = (unsigned)u << 16;
    return v.f;
}

// hardware packed f32->bf16 (RNE), 8 values -> short8
__device__ inline short8 cvt8(const float4& a, const float4& b)
{
    union { unsigned u[4]; short8 s; } r;
    asm("v_cvt_pk_bf16_f32 %0, %1, %2" : "=v"(r.u[0]) : "v"(a.x), "v"(a.y));
    asm("v_cvt_pk_bf16_f32 %0, %1, %2" : "=v"(r.u[1]) : "v"(a.z), "v"(a.w));
    asm("v_cvt_pk_bf16_f32 %0, %1, %2" : "=v"(r.u[2]) : "v"(b.x), "v"(b.y));
    asm("v_cvt_pk_bf16_f32 %0, %1, %2" : "=v"(r.u[3]) : "v"(b.z), "v"(b.w));
    return r.s;
}

// ---------------- weight packing (once per launch, trivial) ----------------
__global__ void pack_w1(const float* __restrict__ W1, short* __restrict__ W1p)
{
    const int id = blockIdx.x * 256 + threadIdx.x;   // 0..4095
    const int kb = id >> 8, n = id & 255;
    short tmp[32];
#pragma unroll
    for (int kl = 0; kl < 32; ++kl)
        tmp[kl] = f2bf(W1[(size_t)(kb * 32 + kl) * N_HID + n]);
    short8* dst = (short8*)&W1p[id * 32];
#pragma unroll
    for (int j = 0; j < 4; ++j) dst[j] = *(short8*)&tmp[j * 8];
}

__global__ void pack_w2(const float* __restrict__ W2, short* __restrict__ W2p)
{
    const int id = blockIdx.x * 256 + threadIdx.x;
    if (id >= 8 * 48) return;
    const int kb = id / 48, n = id % 48;
    short tmp[32];
#pragma unroll
    for (int kl = 0; kl < 32; ++kl)
        tmp[kl] = (n < N_CLASS) ? f2bf(W2[(size_t)(kb * 32 + kl) * N_CLASS + n]) : (short)0;
    short8* dst = (short8*)&W2p[id * 32];
#pragma unroll
    for (int j = 0; j < 4; ++j) dst[j] = *(short8*)&tmp[j * 8];
}

// ---- fused MFMA MLP + hop-0 attention:
//   x0 = bf16(relu(feat@W1+b1)@W2 + b2);  acc = sigmoid(x0.Wa+ba) * x0
// Phase 1: all-register, zero-barrier. Wave owns 32 rows x 128 cols; A loaded
// directly from global (rows are wave-private), hw cvt_pk f32->bf16, fully
// unrolled k-loop with 2-deep A / 1-deep B register pipeline. No LDS use.
// Phase 2: H handoff via LDS (one barrier), small W2 GEMM + fused attention.
__global__ __launch_bounds__(256, 2) void mlp_mfma(
    const float* __restrict__ feat, const short* __restrict__ W1p,
    const float* __restrict__ b1, const short* __restrict__ W2p,
    const float* __restrict__ b2, const float* __restrict__ Wa,
    const float* __restrict__ ba,
    unsigned short* __restrict__ x0, float* __restrict__ acc_out)
{
    __shared__ __align__(16) short smem[64 * 264];          // 33792 B
    short (*Hs)[264] = (short(*)[264])smem;

    const int t    = threadIdx.x;
    const int wave = t >> 6;
    const int lane = t & 63;
    const int q    = lane >> 4;      // quad 0..3
    const int m    = lane & 15;
    const int n0   = blockIdx.x * 64;
    const int RB   = wave >> 1;      // row block (32 rows)
    const int CB   = wave & 1;       // col block (128 cols)

    // wave-private A row pointers (2 row-tiles of 16 rows)
    const float* ap[2];
#pragma unroll
    for (int rt = 0; rt < 2; ++rt) {
        int r = n0 + RB * 32 + rt * 16 + m;
        if (r > N_NODES - 1) r = N_NODES - 1;           // clamp; stores guarded
        ap[rt] = &feat[(size_t)r * N_FEAT + q * 8];
    }
    const short* bp = &W1p[(CB * 128 + m) * 32 + q * 8];

    float4v acc[2][8];
#pragma unroll
    for (int rt = 0; rt < 2; ++rt)
#pragma unroll
        for (int ct = 0; ct < 8; ++ct) acc[rt][ct] = (float4v)0.f;

    float4 A0[3][2], A1[3][2];      // [stage][rt]
    short8 Bp[2][8];                // [stage][ct]

    // prologue: A stages 0,1 (kb=0,1); B stage 0 (kb=0)
#pragma unroll
    for (int s = 0; s < 2; ++s)
#pragma unroll
        for (int rt = 0; rt < 2; ++rt) {
            A0[s][rt] = *(const float4*)(ap[rt] + s * 32);
            A1[s][rt] = *(const float4*)(ap[rt] + s * 32 + 4);
        }
#pragma unroll
    for (int ct = 0; ct < 8; ++ct)
        Bp[0][ct] = *(const short8*)(bp + (ct * 16) * 32);

#pragma unroll
    for (int kb = 0; kb < 16; ++kb) {
        const int sA_ld = (kb + 2) % 3;
        const int sB_ld = (kb + 1) & 1;
        const int sA    = kb % 3;
        const int sB    = kb & 1;
        if (kb + 2 < 16) {
#pragma unroll
            for (int rt = 0; rt < 2; ++rt) {
                A0[sA_ld][rt] = *(const float4*)(ap[rt] + (kb + 2) * 32);
                A1[sA_ld][rt] = *(const float4*)(ap[rt] + (kb + 2) * 32 + 4);
            }
        }
        if (kb + 1 < 16) {
#pragma unroll
            for (int ct = 0; ct < 8; ++ct)
                Bp[sB_ld][ct] = *(const short8*)(bp + ((kb + 1) * 256 + ct * 16) * 32);
        }
        short8 a8[2];
#pragma unroll
        for (int rt = 0; rt < 2; ++rt) a8[rt] = cvt8(A0[sA][rt], A1[sA][rt]);
#pragma unroll
        for (int rt = 0; rt < 2; ++rt)
#pragma unroll
            for (int ct = 0; ct < 8; ++ct)
                acc[rt][ct] = __builtin_amdgcn_mfma_f32_16x16x32_bf16(
                    a8[rt], Bp[sB][ct], acc[rt][ct], 0, 0, 0);
    }

    // H = relu(acc + b1) -> LDS (bf16)
#pragma unroll
    for (int rt = 0; rt < 2; ++rt)
#pragma unroll
        for (int ct = 0; ct < 8; ++ct) {
            const int col = CB * 128 + ct * 16 + m;
            const float bias = b1[col];
            const float4v d = acc[rt][ct];
#pragma unroll
            for (int r = 0; r < 4; ++r) {
                const int row = RB * 32 + rt * 16 + q * 4 + r;
                Hs[row][col] = f2bf(fmaxf(d[r] + bias, 0.f));
            }
        }
    __syncthreads();

    float4v acc2[3];
#pragma unroll
    for (int ct = 0; ct < 3; ++ct) acc2[ct] = (float4v)0.f;
#pragma unroll
    for (int kb = 0; kb < 8; ++kb) {
        const short8 a2 = *(const short8*)&Hs[wave * 16 + m][kb * 32 + q * 8];
#pragma unroll
        for (int ct = 0; ct < 3; ++ct) {
            const int off = (kb * 48 + ct * 16 + m) * 32 + q * 8;
            const short8 b2f = *(const short8*)&W2p[off];
            acc2[ct] = __builtin_amdgcn_mfma_f32_16x16x32_bf16(a2, b2f, acc2[ct], 0, 0, 0);
        }
    }

    // epilogue: x0 write + fused hop-0 attention (acc = sigmoid(x.Wa+ba)*x)
    float val[3][4];
#pragma unroll
    for (int ct = 0; ct < 3; ++ct) {
        const int col = ct * 16 + m;
        const bool cok = col < N_CLASS;
        const float bias = cok ? b2[col] : 0.f;
#pragma unroll
        for (int r = 0; r < 4; ++r) val[ct][r] = acc2[ct][r] + bias;
        if (cok) {
#pragma unroll
            for (int r = 0; r < 4; ++r) {
                const int row = n0 + wave * 16 + q * 4 + r;
                if (row < N_NODES)
                    x0[(size_t)row * N_CLASS + col] = (unsigned short)f2bf(val[ct][r]);
            }
        }
    }
    float part[4];
#pragma unroll
    for (int r = 0; r < 4; ++r) {
        float p = 0.f;
#pragma unroll
        for (int ct = 0; ct < 3; ++ct) {
            const int col = ct * 16 + m;
            if (col < N_CLASS) p += val[ct][r] * Wa[col];
        }
        part[r] = p;
    }
#pragma unroll
    for (int o = 1; o <= 8; o <<= 1)
#pragma unroll
        for (int r = 0; r < 4; ++r) part[r] += __shfl_xor(part[r], o);
    const float bb = ba[0];
#pragma unroll
    for (int r = 0; r < 4; ++r) {
        const int row = n0 + wave * 16 + q * 4 + r;
        if (row < N_NODES) {
            const float sc = 1.f / (1.f + expf(-(part[r] + bb)));
#pragma unroll
            for (int ct = 0; ct < 3; ++ct) {
                const int col = ct * 16 + m;
                if (col < N_CLASS)
                    acc_out[(size_t)row * N_CLASS + col] = sc * val[ct][r];
            }
        }
    }
}

// ---------------- build, phase 1: radix-bin edges by row>>11 ----------------
// Record: [w15:15][row:17][col:17] in a u64.
__global__ __launch_bounds__(256) void bin_kernel(
    const int* __restrict__ erow, const int* __restrict__ ecol,
    const float* __restrict__ ew, int* __restrict__ bin_cursor,
    u64* __restrict__ bins)
{
    __shared__ __align__(16) u64 recs[CHUNK1];   // 32 KB
    __shared__ int hist[NBIN], h2[NBIN], lbase[NBIN], adj[NBIN];

    const int t     = threadIdx.x;
    const int cbase = blockIdx.x * CHUNK1;
    const int e0    = cbase + t * 16;
    const bool has  = e0 < N_EDGES;              // N_EDGES % 16 == 0 -> all-or-nothing
    const int chunk_n = min(CHUNK1, N_EDGES - cbase);

    for (int i = t; i < NBIN; i += 256) { hist[i] = 0; h2[i] = 0; }
    __syncthreads();

    int   rows[16], cols[16], w15[16];
    if (has) {
#pragma unroll
        for (int qv = 0; qv < 4; ++qv) {
            const int4   r = *(const int4*)&erow[e0 + qv * 4];
            const int4   c = *(const int4*)&ecol[e0 + qv * 4];
            const float4 w = *(const float4*)&ew[e0 + qv * 4];
            rows[qv*4+0]=r.x; rows[qv*4+1]=r.y; rows[qv*4+2]=r.z; rows[qv*4+3]=r.w;
            cols[qv*4+0]=c.x; cols[qv*4+1]=c.y; cols[qv*4+2]=c.z; cols[qv*4+3]=c.w;
            const float wf[4] = {w.x, w.y, w.z, w.w};
#pragma unroll
            for (int j = 0; j < 4; ++j) {
                int v = (int)(wf[j] * 32767.f + 0.5f);
                w15[qv*4+j] = (v > 32767) ? 32767 : v;
            }
        }
#pragma unroll
        for (int j = 0; j < 16; ++j)
            atomicAdd(&hist[rows[j] >> BIN_SHIFT], 1);
    }
    __syncthreads();

    if (t == 0) {
        int run = 0;
        for (int b = 0; b < NBIN; ++b) { lbase[b] = run; run += hist[b]; }
    }
    __syncthreads();
    if (t < NBIN) {
        const int g = atomicAdd(&bin_cursor[t], hist[t]);
        adj[t] = g - lbase[t];
    }
    __syncthreads();

    if (has) {
#pragma unroll
        for (int j = 0; j < 16; ++j) {
            const int b = rows[j] >> BIN_SHIFT;
            const int p = lbase[b] + atomicAdd(&h2[b], 1);
            recs[p] = ((u64)w15[j] << 34) | ((u64)rows[j] << 17) | (u64)cols[j];
        }
    }
    __syncthreads();

    for (int i = t; i < chunk_n; i += 256) {
        const u64 r   = recs[i];
        const int row = (int)((r >> 17) & 0x1FFFF);
        const int b   = row >> BIN_SHIFT;
        const int di  = adj[b] + i;                 // = gbase + (i - lbase)
        if (di < BINCAP)
            bins[(size_t)b * BINCAP + di] = r;
    }
}

// ---------------- build, phase 2: per-bin scatter into buckets -------------
// blockIdx = chunk*NBIN_PAD + b; NBIN_PAD % 8 == 0 -> bin b on XCD b&7.
__global__ __launch_bounds__(256) void scatter_bins(
    const int* __restrict__ bin_cursor, const u64* __restrict__ bins,
    int* __restrict__ cnt, unsigned int* __restrict__ ebuck)
{
    const int b = blockIdx.x % NBIN_PAD;
    if (b >= NBIN) return;
    const int chunk = blockIdx.x / NBIN_PAD;
    int n = bin_cursor[b];
    if (n > BINCAP) n = BINCAP;
    const int start = chunk * CHUNK2;
    if (start >= n) return;
    const u64* src = &bins[(size_t)b * BINCAP];

#pragma unroll
    for (int j = 0; j < 16; ++j) {
        const int idx = start + j * 256 + threadIdx.x;
        if (idx < n) {
            const u64 r   = src[idx];
            const int col = (int)(r & 0x1FFFF);
            const int row = (int)((r >> 17) & 0x1FFFF);
            const unsigned rec = ((unsigned)(r >> 34) << 17) | (unsigned)col;
            const int pos = atomicAdd(&cnt[row], 1);
            if (pos < CAP)
                ebuck[(size_t)row * CAP + pos] = rec;
        }
    }
}

// ------- one hop: s = segsum(w * xin[col]) fp32 from bf16 gathers;
//         xout = bf16(s); acc += sigmoid(s.Wa+ba) * s
// wave per row; slot = lane>>3 (8 edges in flight, 640 B/wave), l = lane&7
// (5 active, each loads 16 B = 8 bf16 classes). Records prefetched with one
// coalesced load, broadcast via __shfl.
// LAST: log_softmax fused (acc row in-register); skips xout/acc stores.
template <bool LAST>
__global__ __launch_bounds__(256) void hop_kernel(
    const int* __restrict__ cnt, const unsigned int* __restrict__ ebuck,
    const unsigned short* __restrict__ xin,
    unsigned short* __restrict__ xout, float* __restrict__ acc,
    const float* __restrict__ Wa, const float* __restrict__ ba,
    float* __restrict__ out)
{
    const int lane = threadIdx.x & 63;
    const int row  = blockIdx.x * 4 + (threadIdx.x >> 6);
    if (row >= N_NODES) return;
    const int  slot = lane >> 3;     // 0..7
    const int  l    = lane & 7;      // 0..7; classes [8l, 8l+8) if l<5
    const bool act  = l < 5;

    int n = cnt[row];
    if (n > CAP) n = CAP;
    const size_t ebase = (size_t)row * CAP;

    unsigned rec_a = (lane < n) ? ebuck[ebase + lane] : 0u;

    float s[8];
#pragma unroll
    for (int j = 0; j < 8; ++j) s[j] = 0.f;

    const int nmain = (n < 64) ? n : 64;
    for (int e = 0; e < nmain; e += 8) {
        const unsigned r = __shfl(rec_a, e + slot);
        const int   col  = (int)(r & 0x1FFFFu);
        const float w    = (float)(r >> 17) * (1.f / 32767.f);
        if (act) {
            const ushort8v v = *(const ushort8v*)&xin[(size_t)col * N_CLASS + l * 8];
#pragma unroll
            for (int j = 0; j < 8; ++j) s[j] += w * bf2f(v[j]);
        }
    }
    for (int e = 64; e < n; e += 8) {           // rare tail (deg > 64)
        const int ee = e + slot;
        unsigned r = 0u;
        if (ee < n) r = ebuck[ebase + ee];
        const int   col = (int)(r & 0x1FFFFu);
        const float w   = (float)(r >> 17) * (1.f / 32767.f);
        if (act) {
            const ushort8v v = *(const ushort8v*)&xin[(size_t)col * N_CLASS + l * 8];
#pragma unroll
            for (int j = 0; j < 8; ++j) s[j] += w * bf2f(v[j]);
        }
    }

    // reduce across the 8 slots (xor bits 3,4,5)
#pragma unroll
    for (int o = 8; o <= 32; o <<= 1)
#pragma unroll
        for (int j = 0; j < 8; ++j) s[j] += __shfl_xor(s[j], o);

    // attention score: per-lane partial over its 8 classes, reduce over l
    float tq = 0.f;
    if (act) {
#pragma unroll
        for (int j = 0; j < 8; ++j) tq += s[j] * Wa[l * 8 + j];
    }
#pragma unroll
    for (int o = 1; o <= 4; o <<= 1) tq += __shfl_xor(tq, o);
    const float z  = tq + ba[0];
    const float sc = 1.f / (1.f + expf(-z));

    const bool wr = act && slot == 0;
    if (!LAST) {
        if (wr) {
            ushort8v ov;
#pragma unroll
            for (int j = 0; j < 8; ++j) ov[j] = (unsigned short)f2bf(s[j]);
            *(ushort8v*)&xout[(size_t)row * N_CLASS + l * 8] = ov;

            float4* ap0 = (float4*)&acc[(size_t)row * N_CLASS + l * 8];
            float4 a0 = ap0[0];
            float4 a1 = ap0[1];
            a0.x += sc * s[0]; a0.y += sc * s[1]; a0.z += sc * s[2]; a0.w += sc * s[3];
            a1.x += sc * s[4]; a1.y += sc * s[5]; a1.z += sc * s[6]; a1.w += sc * s[7];
            ap0[0] = a0;
            ap0[1] = a1;
        }
    } else {
        // fused log_softmax over the final attention sum (slot-0 lanes l=0..4)
        float av[8];
        float mxl = -INFINITY;
        if (wr) {
            const float4* ap0 = (const float4*)&acc[(size_t)row * N_CLASS + l * 8];
            const float4 a0 = ap0[0];
            const float4 a1 = ap0[1];
            av[0] = a0.x + sc * s[0]; av[1] = a0.y + sc * s[1];
            av[2] = a0.z + sc * s[2]; av[3] = a0.w + sc * s[3];
            av[4] = a1.x + sc * s[4]; av[5] = a1.y + sc * s[5];
            av[6] = a1.z + sc * s[6]; av[7] = a1.w + sc * s[7];
#pragma unroll
            for (int j = 0; j < 8; ++j) mxl = fmaxf(mxl, av[j]);
        }
        float mx = mxl;
#pragma unroll
        for (int o = 1; o <= 4; o <<= 1) mx = fmaxf(mx, __shfl_xor(mx, o));
        float se = 0.f;
        if (wr) {
#pragma unroll
            for (int j = 0; j < 8; ++j) se += expf(av[j] - mx);
        }
#pragma unroll
        for (int o = 1; o <= 4; o <<= 1) se += __shfl_xor(se, o);
        if (wr) {
            const float ls = logf(se);
            float4 o0, o1;
            o0.x = av[0] - mx - ls; o0.y = av[1] - mx - ls;
            o0.z = av[2] - mx - ls; o0.w = av[3] - mx - ls;
            o1.x = av[4] - mx - ls; o1.y = av[5] - mx - ls;
            o1.z = av[6] - mx - ls; o1.w = av[7] - mx - ls;
            float4* op = (float4*)&out[(size_t)row * N_CLASS + l * 8];
            op[0] = o0;
            op[1] = o1;
        }
    }
}

extern "C" void kernel_launch(void* const* d_in, const int* in_sizes, int n_in,
                              void* d_out, int out_size, void* d_ws, size_t ws_size,
                              hipStream_t stream)
{
    (void)in_sizes; (void)n_in; (void)out_size; (void)ws_size;
    const float* feat = (const float*)d_in[0];
    const int*   erow = (const int*)d_in[1];
    const int*   ecol = (const int*)d_in[2];
    const float* ew   = (const float*)d_in[3];
    const float* W1   = (const float*)d_in[4];
    const float* b1   = (const float*)d_in[5];
    const float* W2   = (const float*)d_in[6];
    const float* b2   = (const float*)d_in[7];
    const float* Wa   = (const float*)d_in[8];
    const float* ba   = (const float*)d_in[9];
    float* out = (float*)d_out;

    char* ws = (char*)d_ws;
    size_t off = 0;
    auto take = [&](size_t bytes) -> char* {
        char* p = ws + off;
        off += (bytes + 255) & ~(size_t)255;
        return p;
    };
    unsigned short* xb0 = (unsigned short*)take((size_t)N_NODES * N_CLASS * 2 + 64);
    unsigned short* xb1 = (unsigned short*)take((size_t)N_NODES * N_CLASS * 2 + 64);
    float*        acc   = (float*)take((size_t)N_NODES * N_CLASS * 4);
    int*          cnt   = (int*)take((size_t)N_NODES * 4);
    int*          bcur  = (int*)take((size_t)NBIN_PAD * 4);
    short*        W1p   = (short*)take((size_t)N_FEAT * N_HID * 2);
    short*        W2p   = (short*)take((size_t)N_HID * 48 * 2);
    unsigned int* ebuck = (unsigned int*)take((size_t)N_NODES * CAP * 4);
    u64*          bins  = (u64*)take((size_t)NBIN * BINCAP * 8);

    hipMemsetAsync(cnt, 0, (size_t)N_NODES * 4, stream);
    hipMemsetAsync(bcur, 0, (size_t)NBIN_PAD * 4, stream);

    pack_w1<<<16, 256, 0, stream>>>(W1, W1p);
    pack_w2<<<2, 256, 0, stream>>>(W2, W2p);
    mlp_mfma<<<(N_NODES + 63) / 64, 256, 0, stream>>>(feat, W1p, b1, W2p, b2,
                                                      Wa, ba, xb0, acc);

    const int nchunk1 = (N_EDGES + CHUNK1 - 1) / CHUNK1;    // 782
    bin_kernel<<<nchunk1, 256, 0, stream>>>(erow, ecol, ew, bcur, bins);
    scatter_bins<<<NBIN_PAD * CPB2, 256, 0, stream>>>(bcur, bins, cnt, ebuck);

    const unsigned short* xin = xb0;
    unsigned short* xout = xb1;
    for (int k = 0; k < K_HOPS - 1; ++k) {
        hop_kernel<false><<<N_NODES / 4, 256, 0, stream>>>(
            cnt, ebuck, xin, xout, acc, Wa, ba, out);
        unsigned short* tmp = (unsigned short*)xin;
        xin  = xout;
        xout = tmp;
    }
    hop_kernel<true><<<N_NODES / 4, 256, 0, stream>>>(
        cnt, ebuck, xin, xout, acc, Wa, ba, out);
}

// Round 5
// 1162.172 us; speedup vs baseline: 1.1170x; 1.0328x over previous
//
#include <hip/hip_runtime.h>
#include <math.h>

#define N_NODES 100000
#define N_EDGES 3200000
#define N_FEAT  512
#define N_HID   256
#define N_CLASS 40
#define K_HOPS  10

#define CAP        80                   // bucket capacity (Poisson(32); P(>80)~1e-11)

// two-phase binned build
#define BIN_SHIFT  11
#define NBIN       49                   // ceil(100000 / 2048)
#define NBIN_PAD   56                   // multiple of 8 -> bin b always on XCD b&7
#define BINCAP     68000                // mean 65536, sigma ~253 -> +9.7 sigma
#define CHUNK1     4096                 // edges per phase-1 block
#define CHUNK2     4096                 // records per phase-2 block
#define CPB2       17                   // 17*4096 = 69632 >= BINCAP

typedef __attribute__((ext_vector_type(8))) short short8;
typedef __attribute__((ext_vector_type(8))) unsigned short ushort8v;
typedef __attribute__((ext_vector_type(4))) float float4v;
typedef unsigned long long u64;

__device__ inline short f2bf(float f)
{
    union { float f; unsigned u; } v; v.f = f;
    unsigned r = v.u + 0x7FFF + ((v.u >> 16) & 1);   // RNE
    return (short)(r >> 16);
}

__device__ inline float bf2f(unsigned short u)
{
    union { unsigned u; float f; } v; v.u = (unsigned)u << 16;
    return v.f;
}

// hardware packed f32->bf16 (RNE), 8 values -> short8
__device__ inline short8 cvt8(const float4& a, const float4& b)
{
    union { unsigned u[4]; short8 s; } r;
    asm("v_cvt_pk_bf16_f32 %0, %1, %2" : "=v"(r.u[0]) : "v"(a.x), "v"(a.y));
    asm("v_cvt_pk_bf16_f32 %0, %1, %2" : "=v"(r.u[1]) : "v"(a.z), "v"(a.w));
    asm("v_cvt_pk_bf16_f32 %0, %1, %2" : "=v"(r.u[2]) : "v"(b.x), "v"(b.y));
    asm("v_cvt_pk_bf16_f32 %0, %1, %2" : "=v"(r.u[3]) : "v"(b.z), "v"(b.w));
    return r.s;
}

// async global->LDS, 16 B/lane, LDS dest = uniform base + lane*16 (linear)
__device__ inline void gload_lds16(const void* g, void* l)
{
    __builtin_amdgcn_global_load_lds(
        (const __attribute__((address_space(1))) unsigned*)g,
        (__attribute__((address_space(3))) unsigned*)l, 16, 0, 0);
}

// ---------------- weight packing (once per launch, trivial) ----------------
__global__ void pack_w1(const float* __restrict__ W1, short* __restrict__ W1p)
{
    const int id = blockIdx.x * 256 + threadIdx.x;   // 0..4095
    const int kb = id >> 8, n = id & 255;
    short tmp[32];
#pragma unroll
    for (int kl = 0; kl < 32; ++kl)
        tmp[kl] = f2bf(W1[(size_t)(kb * 32 + kl) * N_HID + n]);
    short8* dst = (short8*)&W1p[id * 32];
#pragma unroll
    for (int j = 0; j < 4; ++j) dst[j] = *(short8*)&tmp[j * 8];
}

__global__ void pack_w2(const float* __restrict__ W2, short* __restrict__ W2p)
{
    const int id = blockIdx.x * 256 + threadIdx.x;
    if (id >= 8 * 48) return;
    const int kb = id / 48, n = id % 48;
    short tmp[32];
#pragma unroll
    for (int kl = 0; kl < 32; ++kl)
        tmp[kl] = (n < N_CLASS) ? f2bf(W2[(size_t)(kb * 32 + kl) * N_CLASS + n]) : (short)0;
    short8* dst = (short8*)&W2p[id * 32];
#pragma unroll
    for (int j = 0; j < 4; ++j) dst[j] = *(short8*)&tmp[j * 8];
}

// ---- fused MFMA MLP + hop-0 attention:
//   x0 = bf16(relu(feat@W1+b1)@W2 + b2);  acc = sigmoid(x0.Wa+ba) * x0
// Phase 1 (R2 tile structure + m97 async staging): A staged f32 via
// global_load_lds, double-buffered 2x8KB, ONE barrier/k-step. LDS dest is
// linear; the GLOBAL source is pre-swizzled (g ^= row&7 per 16B group) so the
// stride-128B ds_reads are ~2-way instead of 16-way bank conflicts; the same
// XOR is applied on the read side. f32->bf16 at the ds_read->MFMA boundary
// via v_cvt_pk_bf16_f32.
__global__ __launch_bounds__(256) void mlp_mfma(
    const float* __restrict__ feat, const short* __restrict__ W1p,
    const float* __restrict__ b1, const short* __restrict__ W2p,
    const float* __restrict__ b2, const float* __restrict__ Wa,
    const float* __restrict__ ba,
    unsigned short* __restrict__ x0, float* __restrict__ acc_out)
{
    __shared__ __align__(16) short smem[64 * 264];   // 33792 B
    char* abase      = (char*)smem;                  // phase 1: 2 x 8 KB A-tile f32
    short (*Hs)[264] = (short(*)[264])smem;          // phase 2 (aliased)

    const int t    = threadIdx.x;
    const int wave = t >> 6;
    const int lane = t & 63;
    const int q    = lane >> 4;      // quad 0..3
    const int m    = lane & 15;
    const int n0   = blockIdx.x * 64;
    const int colbase = wave * 64;

    // staging: wave w stages rows [16w,16w+16) as 2 instrs of 8 rows each.
    // lane i covers row (i>>3), 16B-group (i&7); source group pre-swizzled.
    const int gg = (lane & 7) ^ ((lane >> 3) & 7);
    const float* sp[2];
#pragma unroll
    for (int s2 = 0; s2 < 2; ++s2) {
        int r = n0 + wave * 16 + s2 * 8 + (lane >> 3);
        if (r > N_NODES - 1) r = N_NODES - 1;        // clamp; stores guarded
        sp[s2] = &feat[(size_t)r * N_FEAT + gg * 4];
    }
    char* lbase = abase + wave * 2048;

    float4v acc[4][4];
#pragma unroll
    for (int i = 0; i < 4; ++i)
#pragma unroll
        for (int j = 0; j < 4; ++j) acc[i][j] = (float4v)0.f;

    // prologue: stage k-tile 0 into buf 0
    gload_lds16(sp[0], lbase);
    gload_lds16(sp[1], lbase + 1024);
    __syncthreads();

    for (int kb = 0; kb < 16; ++kb) {
        if (kb < 15) {
            char* lb = lbase + ((kb + 1) & 1) * 8192;
            gload_lds16(sp[0] + (kb + 1) * 32, lb);
            gload_lds16(sp[1] + (kb + 1) * 32, lb + 1024);
        }
        const char* ab = abase + (kb & 1) * 8192;
        short8 af[4], bfr[4];
#pragma unroll
        for (int rt = 0; rt < 4; ++rt) {
            const int rowL = rt * 16 + m;
            const float4 fa = *(const float4*)(ab + rowL * 128 + ((2 * q)     ^ (m & 7)) * 16);
            const float4 fb = *(const float4*)(ab + rowL * 128 + ((2 * q + 1) ^ (m & 7)) * 16);
            af[rt] = cvt8(fa, fb);
        }
#pragma unroll
        for (int ct = 0; ct < 4; ++ct) {
            const int off = (kb * 256 + colbase + ct * 16 + m) * 32 + q * 8;
            bfr[ct] = *(const short8*)&W1p[off];
        }
#pragma unroll
        for (int rt = 0; rt < 4; ++rt)
#pragma unroll
            for (int ct = 0; ct < 4; ++ct)
                acc[rt][ct] = __builtin_amdgcn_mfma_f32_16x16x32_bf16(
                    af[rt], bfr[ct], acc[rt][ct], 0, 0, 0);
        __syncthreads();    // drains vmcnt -> next buf ready; also guards reuse
    }

    // phase 1 epilogue: H = relu(acc + b1) -> LDS (bf16)
#pragma unroll
    for (int ct = 0; ct < 4; ++ct) {
        const int col = colbase + ct * 16 + m;
        const float bias = b1[col];
#pragma unroll
        for (int rt = 0; rt < 4; ++rt) {
            const float4v d = acc[rt][ct];
#pragma unroll
            for (int r = 0; r < 4; ++r) {
                const float hv = fmaxf(d[r] + bias, 0.f);
                Hs[rt * 16 + q * 4 + r][col] = f2bf(hv);
            }
        }
    }
    __syncthreads();

    float4v acc2[3];
#pragma unroll
    for (int ct = 0; ct < 3; ++ct) acc2[ct] = (float4v)0.f;
#pragma unroll
    for (int kb = 0; kb < 8; ++kb) {
        const short8 a2 = *(const short8*)&Hs[wave * 16 + m][kb * 32 + q * 8];
#pragma unroll
        for (int ct = 0; ct < 3; ++ct) {
            const int off = (kb * 48 + ct * 16 + m) * 32 + q * 8;
            const short8 b2f = *(const short8*)&W2p[off];
            acc2[ct] = __builtin_amdgcn_mfma_f32_16x16x32_bf16(a2, b2f, acc2[ct], 0, 0, 0);
        }
    }

    // epilogue: x0 write + fused hop-0 attention (acc = sigmoid(x.Wa+ba)*x)
    float val[3][4];
#pragma unroll
    for (int ct = 0; ct < 3; ++ct) {
        const int col = ct * 16 + m;
        const bool cok = col < N_CLASS;
        const float bias = cok ? b2[col] : 0.f;
#pragma unroll
        for (int r = 0; r < 4; ++r) val[ct][r] = acc2[ct][r] + bias;
        if (cok) {
#pragma unroll
            for (int r = 0; r < 4; ++r) {
                const int row = n0 + wave * 16 + q * 4 + r;
                if (row < N_NODES)
                    x0[(size_t)row * N_CLASS + col] = (unsigned short)f2bf(val[ct][r]);
            }
        }
    }
    float part[4];
#pragma unroll
    for (int r = 0; r < 4; ++r) {
        float p = 0.f;
#pragma unroll
        for (int ct = 0; ct < 3; ++ct) {
            const int col = ct * 16 + m;
            if (col < N_CLASS) p += val[ct][r] * Wa[col];
        }
        part[r] = p;
    }
#pragma unroll
    for (int o = 1; o <= 8; o <<= 1)
#pragma unroll
        for (int r = 0; r < 4; ++r) part[r] += __shfl_xor(part[r], o);
    const float bb = ba[0];
#pragma unroll
    for (int r = 0; r < 4; ++r) {
        const int row = n0 + wave * 16 + q * 4 + r;
        if (row < N_NODES) {
            const float sc = 1.f / (1.f + expf(-(part[r] + bb)));
#pragma unroll
            for (int ct = 0; ct < 3; ++ct) {
                const int col = ct * 16 + m;
                if (col < N_CLASS)
                    acc_out[(size_t)row * N_CLASS + col] = sc * val[ct][r];
            }
        }
    }
}

// ---------------- build, phase 1: radix-bin edges by row>>11 ----------------
// Record: [w15:15][row:17][col:17] in a u64.
__global__ __launch_bounds__(256) void bin_kernel(
    const int* __restrict__ erow, const int* __restrict__ ecol,
    const float* __restrict__ ew, int* __restrict__ bin_cursor,
    u64* __restrict__ bins)
{
    __shared__ __align__(16) u64 recs[CHUNK1];   // 32 KB
    __shared__ int hist[NBIN], h2[NBIN], lbase[NBIN], adj[NBIN];

    const int t     = threadIdx.x;
    const int cbase = blockIdx.x * CHUNK1;
    const int e0    = cbase + t * 16;
    const bool has  = e0 < N_EDGES;              // N_EDGES % 16 == 0 -> all-or-nothing
    const int chunk_n = min(CHUNK1, N_EDGES - cbase);

    for (int i = t; i < NBIN; i += 256) { hist[i] = 0; h2[i] = 0; }
    __syncthreads();

    int   rows[16], cols[16], w15[16];
    if (has) {
#pragma unroll
        for (int qv = 0; qv < 4; ++qv) {
            const int4   r = *(const int4*)&erow[e0 + qv * 4];
            const int4   c = *(const int4*)&ecol[e0 + qv * 4];
            const float4 w = *(const float4*)&ew[e0 + qv * 4];
            rows[qv*4+0]=r.x; rows[qv*4+1]=r.y; rows[qv*4+2]=r.z; rows[qv*4+3]=r.w;
            cols[qv*4+0]=c.x; cols[qv*4+1]=c.y; cols[qv*4+2]=c.z; cols[qv*4+3]=c.w;
            const float wf[4] = {w.x, w.y, w.z, w.w};
#pragma unroll
            for (int j = 0; j < 4; ++j) {
                int v = (int)(wf[j] * 32767.f + 0.5f);
                w15[qv*4+j] = (v > 32767) ? 32767 : v;
            }
        }
#pragma unroll
        for (int j = 0; j < 16; ++j)
            atomicAdd(&hist[rows[j] >> BIN_SHIFT], 1);
    }
    __syncthreads();

    if (t == 0) {
        int run = 0;
        for (int b = 0; b < NBIN; ++b) { lbase[b] = run; run += hist[b]; }
    }
    __syncthreads();
    if (t < NBIN) {
        const int g = atomicAdd(&bin_cursor[t], hist[t]);
        adj[t] = g - lbase[t];
    }
    __syncthreads();

    if (has) {
#pragma unroll
        for (int j = 0; j < 16; ++j) {
            const int b = rows[j] >> BIN_SHIFT;
            const int p = lbase[b] + atomicAdd(&h2[b], 1);
            recs[p] = ((u64)w15[j] << 34) | ((u64)rows[j] << 17) | (u64)cols[j];
        }
    }
    __syncthreads();

    for (int i = t; i < chunk_n; i += 256) {
        const u64 r   = recs[i];
        const int row = (int)((r >> 17) & 0x1FFFF);
        const int b   = row >> BIN_SHIFT;
        const int di  = adj[b] + i;                 // = gbase + (i - lbase)
        if (di < BINCAP)
            bins[(size_t)b * BINCAP + di] = r;
    }
}

// ---------------- build, phase 2: per-bin scatter into buckets -------------
// blockIdx = chunk*NBIN_PAD + b; NBIN_PAD % 8 == 0 -> bin b on XCD b&7.
__global__ __launch_bounds__(256) void scatter_bins(
    const int* __restrict__ bin_cursor, const u64* __restrict__ bins,
    int* __restrict__ cnt, unsigned int* __restrict__ ebuck)
{
    const int b = blockIdx.x % NBIN_PAD;
    if (b >= NBIN) return;
    const int chunk = blockIdx.x / NBIN_PAD;
    int n = bin_cursor[b];
    if (n > BINCAP) n = BINCAP;
    const int start = chunk * CHUNK2;
    if (start >= n) return;
    const u64* src = &bins[(size_t)b * BINCAP];

#pragma unroll
    for (int j = 0; j < 16; ++j) {
        const int idx = start + j * 256 + threadIdx.x;
        if (idx < n) {
            const u64 r   = src[idx];
            const int col = (int)(r & 0x1FFFF);
            const int row = (int)((r >> 17) & 0x1FFFF);
            const unsigned rec = ((unsigned)(r >> 34) << 17) | (unsigned)col;
            const int pos = atomicAdd(&cnt[row], 1);
            if (pos < CAP)
                ebuck[(size_t)row * CAP + pos] = rec;
        }
    }
}

// ------- one hop: s = segsum(w * xin[col]) fp32 from bf16 gathers;
//         xout = bf16(s); acc += sigmoid(s.Wa+ba) * s
// wave per row; slot = lane>>3 (8 edges/iter), l = lane&7 (5 active, 16 B
// gathers). n is WAVE-UNIFORM -> fully unrolled 8 iterations with uniform
// guards: ALL gathers issue before the first FMA (T14 issue-early, static
// indexing). LAST: log_softmax fused; skips xout/acc stores.
template <bool LAST>
__global__ __launch_bounds__(256) void hop_kernel(
    const int* __restrict__ cnt, const unsigned int* __restrict__ ebuck,
    const unsigned short* __restrict__ xin,
    unsigned short* __restrict__ xout, float* __restrict__ acc,
    const float* __restrict__ Wa, const float* __restrict__ ba,
    float* __restrict__ out)
{
    const int lane = threadIdx.x & 63;
    const int row  = blockIdx.x * 4 + (threadIdx.x >> 6);
    if (row >= N_NODES) return;
    const int  slot = lane >> 3;     // 0..7
    const int  l    = lane & 7;      // 0..7; classes [8l, 8l+8) if l<5
    const bool act  = l < 5;

    int n = cnt[row];
    if (n > CAP) n = CAP;
    const size_t ebase = (size_t)row * CAP;

    unsigned rec_a = (lane < n) ? ebuck[ebase + lane] : 0u;

    const int nit = ((n < 64 ? n : 64) + 7) >> 3;    // 0..8, wave-uniform

    float    w[8];
    ushort8v v[8];
    // issue ALL gathers up-front (uniform guards, static indices)
#pragma unroll
    for (int it = 0; it < 8; ++it) {
        if (it < nit) {
            const unsigned r = __shfl(rec_a, it * 8 + slot);
            w[it] = (float)(r >> 17) * (1.f / 32767.f);
            const int col = (int)(r & 0x1FFFFu);
            if (act)
                v[it] = *(const ushort8v*)&xin[(size_t)col * N_CLASS + l * 8];
        }
    }

    float s[8];
#pragma unroll
    for (int j = 0; j < 8; ++j) s[j] = 0.f;

#pragma unroll
    for (int it = 0; it < 8; ++it) {
        if (it < nit) {
            if (act) {
#pragma unroll
                for (int j = 0; j < 8; ++j) s[j] += w[it] * bf2f(v[it][j]);
            }
        }
    }

    for (int e = 64; e < n; e += 8) {           // rare tail (deg > 64)
        const int ee = e + slot;
        unsigned r = 0u;
        if (ee < n) r = ebuck[ebase + ee];
        const int   col = (int)(r & 0x1FFFFu);
        const float wt  = (float)(r >> 17) * (1.f / 32767.f);
        if (act) {
            const ushort8v vt = *(const ushort8v*)&xin[(size_t)col * N_CLASS + l * 8];
#pragma unroll
            for (int j = 0; j < 8; ++j) s[j] += wt * bf2f(vt[j]);
        }
    }

    // reduce across the 8 slots (xor bits 3,4,5)
#pragma unroll
    for (int o = 8; o <= 32; o <<= 1)
#pragma unroll
        for (int j = 0; j < 8; ++j) s[j] += __shfl_xor(s[j], o);

    // attention score: per-lane partial over its 8 classes, reduce over l
    float tq = 0.f;
    if (act) {
#pragma unroll
        for (int j = 0; j < 8; ++j) tq += s[j] * Wa[l * 8 + j];
    }
#pragma unroll
    for (int o = 1; o <= 4; o <<= 1) tq += __shfl_xor(tq, o);
    const float z  = tq + ba[0];
    const float sc = 1.f / (1.f + expf(-z));

    const bool wr = act && slot == 0;
    if (!LAST) {
        if (wr) {
            ushort8v ov;
#pragma unroll
            for (int j = 0; j < 8; ++j) ov[j] = (unsigned short)f2bf(s[j]);
            *(ushort8v*)&xout[(size_t)row * N_CLASS + l * 8] = ov;

            float4* ap0 = (float4*)&acc[(size_t)row * N_CLASS + l * 8];
            float4 a0 = ap0[0];
            float4 a1 = ap0[1];
            a0.x += sc * s[0]; a0.y += sc * s[1]; a0.z += sc * s[2]; a0.w += sc * s[3];
            a1.x += sc * s[4]; a1.y += sc * s[5]; a1.z += sc * s[6]; a1.w += sc * s[7];
            ap0[0] = a0;
            ap0[1] = a1;
        }
    } else {
        // fused log_softmax over the final attention sum (slot-0 lanes l=0..4)
        float av[8];
        float mxl = -INFINITY;
        if (wr) {
            const float4* ap0 = (const float4*)&acc[(size_t)row * N_CLASS + l * 8];
            const float4 a0 = ap0[0];
            const float4 a1 = ap0[1];
            av[0] = a0.x + sc * s[0]; av[1] = a0.y + sc * s[1];
            av[2] = a0.z + sc * s[2]; av[3] = a0.w + sc * s[3];
            av[4] = a1.x + sc * s[4]; av[5] = a1.y + sc * s[5];
            av[6] = a1.z + sc * s[6]; av[7] = a1.w + sc * s[7];
#pragma unroll
            for (int j = 0; j < 8; ++j) mxl = fmaxf(mxl, av[j]);
        }
        float mx = mxl;
#pragma unroll
        for (int o = 1; o <= 4; o <<= 1) mx = fmaxf(mx, __shfl_xor(mx, o));
        float se = 0.f;
        if (wr) {
#pragma unroll
            for (int j = 0; j < 8; ++j) se += expf(av[j] - mx);
        }
#pragma unroll
        for (int o = 1; o <= 4; o <<= 1) se += __shfl_xor(se, o);
        if (wr) {
            const float ls = logf(se);
            float4 o0, o1;
            o0.x = av[0] - mx - ls; o0.y = av[1] - mx - ls;
            o0.z = av[2] - mx - ls; o0.w = av[3] - mx - ls;
            o1.x = av[4] - mx - ls; o1.y = av[5] - mx - ls;
            o1.z = av[6] - mx - ls; o1.w = av[7] - mx - ls;
            float4* op = (float4*)&out[(size_t)row * N_CLASS + l * 8];
            op[0] = o0;
            op[1] = o1;
        }
    }
}

extern "C" void kernel_launch(void* const* d_in, const int* in_sizes, int n_in,
                              void* d_out, int out_size, void* d_ws, size_t ws_size,
                              hipStream_t stream)
{
    (void)in_sizes; (void)n_in; (void)out_size; (void)ws_size;
    const float* feat = (const float*)d_in[0];
    const int*   erow = (const int*)d_in[1];
    const int*   ecol = (const int*)d_in[2];
    const float* ew   = (const float*)d_in[3];
    const float* W1   = (const float*)d_in[4];
    const float* b1   = (const float*)d_in[5];
    const float* W2   = (const float*)d_in[6];
    const float* b2   = (const float*)d_in[7];
    const float* Wa   = (const float*)d_in[8];
    const float* ba   = (const float*)d_in[9];
    float* out = (float*)d_out;

    char* ws = (char*)d_ws;
    size_t off = 0;
    auto take = [&](size_t bytes) -> char* {
        char* p = ws + off;
        off += (bytes + 255) & ~(size_t)255;
        return p;
    };
    unsigned short* xb0 = (unsigned short*)take((size_t)N_NODES * N_CLASS * 2 + 64);
    unsigned short* xb1 = (unsigned short*)take((size_t)N_NODES * N_CLASS * 2 + 64);
    float*        acc   = (float*)take((size_t)N_NODES * N_CLASS * 4);
    int*          cnt   = (int*)take((size_t)N_NODES * 4);
    int*          bcur  = (int*)take((size_t)NBIN_PAD * 4);
    short*        W1p   = (short*)take((size_t)N_FEAT * N_HID * 2);
    short*        W2p   = (short*)take((size_t)N_HID * 48 * 2);
    unsigned int* ebuck = (unsigned int*)take((size_t)N_NODES * CAP * 4);
    u64*          bins  = (u64*)take((size_t)NBIN * BINCAP * 8);

    hipMemsetAsync(cnt, 0, (size_t)N_NODES * 4, stream);
    hipMemsetAsync(bcur, 0, (size_t)NBIN_PAD * 4, stream);

    pack_w1<<<16, 256, 0, stream>>>(W1, W1p);
    pack_w2<<<2, 256, 0, stream>>>(W2, W2p);
    mlp_mfma<<<(N_NODES + 63) / 64, 256, 0, stream>>>(feat, W1p, b1, W2p, b2,
                                                      Wa, ba, xb0, acc);

    const int nchunk1 = (N_EDGES + CHUNK1 - 1) / CHUNK1;    // 782
    bin_kernel<<<nchunk1, 256, 0, stream>>>(erow, ecol, ew, bcur, bins);
    scatter_bins<<<NBIN_PAD * CPB2, 256, 0, stream>>>(bcur, bins, cnt, ebuck);

    const unsigned short* xin = xb0;
    unsigned short* xout = xb1;
    for (int k = 0; k < K_HOPS - 1; ++k) {
        hop_kernel<false><<<N_NODES / 4, 256, 0, stream>>>(
            cnt, ebuck, xin, xout, acc, Wa, ba, out);
        unsigned short* tmp = (unsigned short*)xin;
        xin  = xout;
        xout = tmp;
    }
    hop_kernel<true><<<N_NODES / 4, 256, 0, stream>>>(
        cnt, ebuck, xin, xout, acc, Wa, ba, out);
}